// Round 1
// 3067.779 us; speedup vs baseline: 3.0179x; 3.0179x over previous
//
#include <hip/hip_runtime.h>

typedef __bf16 bf16;
typedef __bf16 bf16x8 __attribute__((ext_vector_type(8)));
typedef float  f32x4  __attribute__((ext_vector_type(4)));
typedef unsigned int       u32;
typedef unsigned short     u16;
typedef unsigned long long u64;

__device__ __forceinline__ f32x4 mfma16(bf16x8 a, bf16x8 b, f32x4 c) {
  return __builtin_amdgcn_mfma_f32_16x16x32_bf16(a, b, c, 0, 0, 0);
}
__device__ __forceinline__ float sigm(float x)  { return 1.0f / (1.0f + __expf(-x)); }
__device__ __forceinline__ float tanh_(float x) { return 2.0f / (1.0f + __expf(-2.0f * x)) - 1.0f; }
__device__ __forceinline__ float softplus_(float x) {
  return fmaxf(x, 0.0f) + __logf(1.0f + __expf(-fabsf(x)));
}
__device__ __forceinline__ float leaky_(float x) { return x > 0.0f ? x : 0.01f * x; }
__device__ __forceinline__ u16 bfbits(float f) { return __builtin_bit_cast(u16, (bf16)f); }

// ---------------- prep kernels (fp32 in -> bf16 out) ----------------

__global__ void k_transpose(const float* __restrict__ src, bf16* __restrict__ dst, int K, int N) {
  int i = blockIdx.x * 256 + threadIdx.x;
  if (i < K * N) { int k = i / N; int n = i - k * N; dst[n * K + k] = (bf16)src[i]; }
}

__global__ void k_p2(const float* __restrict__ pred, const float* __restrict__ dp, bf16* __restrict__ P2T) {
  int i = blockIdx.x * 256 + threadIdx.x;   // 65536
  int irow = i >> 8, n = i & 255;
  float acc = 0.0f;
  for (int j = 0; j < 256; ++j) {
    float p = pred[irow * 256 + j] - (j == irow ? 1.0f : 0.0f);
    acc += p * dp[j * 256 + n];
  }
  P2T[n * 256 + irow] = (bf16)acc;
}

__global__ void k_p1(const float* __restrict__ pred, const float* __restrict__ g1, bf16* __restrict__ P1T) {
  int i = blockIdx.x * 256 + threadIdx.x;   // 8192
  int irow = i >> 5, n = i & 31;
  float acc = 0.0f;
  for (int j = 0; j < 256; ++j) {
    float p = pred[irow * 256 + j] - (j == irow ? 1.0f : 0.0f);
    acc += p * g1[j * 32 + n];
  }
  P1T[n * 256 + irow] = (bf16)acc;
}

__global__ void k_cvec(const float* __restrict__ pred_b, const float* __restrict__ dp,
                       const float* __restrict__ g1, const float* __restrict__ g1_b,
                       float* __restrict__ c2f, float* __restrict__ c1f) {
  int n = threadIdx.x;  // 256 threads
  float acc = 0.0f;
  for (int j = 0; j < 256; ++j) acc += pred_b[j] * dp[j * 256 + n];
  c2f[n] = acc;
  if (n < 32) {
    float a2 = 0.0f;
    for (int j = 0; j < 256; ++j) a2 += pred_b[j] * g1[j * 32 + n];
    c1f[n] = a2 + g1_b[n];
  }
}

__global__ void k_zero(u32* __restrict__ p, int n) {
  int i = blockIdx.x * 256 + threadIdx.x;
  if (i < n) p[i] = 0;
}

// ---------------- phase 1: x = leaky(leaky(LN(obs@obs_W+b))@enc_W+b)@pre_W+b) ----------------

__global__ __launch_bounds__(256, 2) void k_phase1(
    const float* __restrict__ obs,
    const bf16* __restrict__ obs_WT, const bf16* __restrict__ enc_WT, const bf16* __restrict__ pre_WT,
    const float* __restrict__ obs_b, const float* __restrict__ enc_b, const float* __restrict__ pre_b,
    float* __restrict__ out)
{
  const int tid  = threadIdx.x;
  const int lane = tid & 63;
  const int w    = tid >> 6;       // wave 0..3
  const int n16  = lane & 15, quad = lane >> 4;
  const long R0  = (long)blockIdx.x * 64;

  __shared__ __align__(16) bf16 obsb[64][72];
  __shared__ __align__(16) bf16 ebuf[64][264];
  __shared__ __align__(16) bf16 e2buf[64][264];
  __shared__ float red[64][8];

  { // load obs tile 64x64 (fp32 -> bf16)
    int row = tid >> 2, col = (tid & 3) * 16;
    const float* src = obs + (R0 + row) * 64 + col;
    #pragma unroll
    for (int q = 0; q < 16; ++q) obsb[row][col + q] = (bf16)src[q];
  }
  __syncthreads();

  // G1: e0 = obs @ obs_W + obs_b  (K=64)
  {
    f32x4 acc[4][4] = {};
    #pragma unroll
    for (int ks = 0; ks < 2; ++ks) {
      bf16x8 a[4];
      #pragma unroll
      for (int mt = 0; mt < 4; ++mt) a[mt] = *(const bf16x8*)&obsb[mt * 16 + n16][ks * 32 + quad * 8];
      #pragma unroll
      for (int nt = 0; nt < 4; ++nt) {
        int ncol = (4 * w + nt) * 16 + n16;
        bf16x8 b = *(const bf16x8*)(obs_WT + ncol * 64 + ks * 32 + quad * 8);
        #pragma unroll
        for (int mt = 0; mt < 4; ++mt) acc[mt][nt] = mfma16(a[mt], b, acc[mt][nt]);
      }
    }
    #pragma unroll
    for (int nt = 0; nt < 4; ++nt) {
      int ncol = (4 * w + nt) * 16 + n16;
      float bb = obs_b[ncol];
      #pragma unroll
      for (int mt = 0; mt < 4; ++mt)
        #pragma unroll
        for (int reg = 0; reg < 4; ++reg)
          ebuf[mt * 16 + quad * 4 + reg][ncol] = (bf16)(acc[mt][nt][reg] + bb);
    }
  }
  __syncthreads();
  // LayerNorm over 256 (no affine)
  {
    int row = tid >> 2, qt = tid & 3;
    float s = 0, s2 = 0;
    for (int c = 0; c < 64; ++c) { float v = (float)ebuf[row][qt * 64 + c]; s += v; s2 += v * v; }
    red[row][qt] = s; red[row][4 + qt] = s2;
  }
  __syncthreads();
  if (tid < 64) {
    float s  = red[tid][0] + red[tid][1] + red[tid][2] + red[tid][3];
    float s2 = red[tid][4] + red[tid][5] + red[tid][6] + red[tid][7];
    float mu = s * (1.0f / 256.0f);
    float var = s2 * (1.0f / 256.0f) - mu * mu;
    red[tid][0] = mu; red[tid][1] = rsqrtf(var + 1e-5f);
  }
  __syncthreads();
  {
    int row = tid >> 2, qt = tid & 3;
    float mu = red[row][0], rstd = red[row][1];
    for (int c = 0; c < 64; ++c) {
      int cc = qt * 64 + c;
      ebuf[row][cc] = (bf16)(((float)ebuf[row][cc] - mu) * rstd);
    }
  }
  __syncthreads();
  // G2: e1 = leaky(e0n @ enc_W + enc_b)
  {
    f32x4 acc[4][4] = {};
    #pragma unroll
    for (int ks = 0; ks < 8; ++ks) {
      bf16x8 a[4];
      #pragma unroll
      for (int mt = 0; mt < 4; ++mt) a[mt] = *(const bf16x8*)&ebuf[mt * 16 + n16][ks * 32 + quad * 8];
      #pragma unroll
      for (int nt = 0; nt < 4; ++nt) {
        int ncol = (4 * w + nt) * 16 + n16;
        bf16x8 b = *(const bf16x8*)(enc_WT + ncol * 256 + ks * 32 + quad * 8);
        #pragma unroll
        for (int mt = 0; mt < 4; ++mt) acc[mt][nt] = mfma16(a[mt], b, acc[mt][nt]);
      }
    }
    #pragma unroll
    for (int nt = 0; nt < 4; ++nt) {
      int ncol = (4 * w + nt) * 16 + n16;
      float bb = enc_b[ncol];
      #pragma unroll
      for (int mt = 0; mt < 4; ++mt)
        #pragma unroll
        for (int reg = 0; reg < 4; ++reg)
          e2buf[mt * 16 + quad * 4 + reg][ncol] = (bf16)leaky_(acc[mt][nt][reg] + bb);
    }
  }
  __syncthreads();
  // G3: x = leaky(e1 @ pre_W + pre_b) -> global fp32 (d_out doubles as x buffer)
  {
    f32x4 acc[4][4] = {};
    #pragma unroll
    for (int ks = 0; ks < 8; ++ks) {
      bf16x8 a[4];
      #pragma unroll
      for (int mt = 0; mt < 4; ++mt) a[mt] = *(const bf16x8*)&e2buf[mt * 16 + n16][ks * 32 + quad * 8];
      #pragma unroll
      for (int nt = 0; nt < 4; ++nt) {
        int ncol = (4 * w + nt) * 16 + n16;
        bf16x8 b = *(const bf16x8*)(pre_WT + ncol * 256 + ks * 32 + quad * 8);
        #pragma unroll
        for (int mt = 0; mt < 4; ++mt) acc[mt][nt] = mfma16(a[mt], b, acc[mt][nt]);
      }
    }
    #pragma unroll
    for (int nt = 0; nt < 4; ++nt) {
      int ncol = (4 * w + nt) * 16 + n16;
      float bb = pre_b[ncol];
      #pragma unroll
      for (int mt = 0; mt < 4; ++mt)
        #pragma unroll
        for (int reg = 0; reg < 4; ++reg)
          out[(R0 + mt * 16 + quad * 4 + reg) * 256 + ncol] = leaky_(acc[mt][nt][reg] + bb);
    }
  }
}

// ---------------- phase 2: column-split persistent recurrent scan ----------------
// 256 wgs x 256 thr (4 waves). Group g = bid>>2 owns batch rows 16g..16g+15;
// quarter q = bid&3 owns h-cols [64q,64q+64). Wave w owns col c = 64q+16w+n16.
// Own-column h state (fp32) lives in registers (4 rows/lane). Per step the two
// cross-column couplings are exchanged through the MALL via relaxed agent-scope
// atomics + per-group monotonic flags:
//   rh = r*h (bf16, packed u64)  -> rhx buffer   (needed by Wn GEMM, K=[x|rh])
//   h_new (fp32)                 -> rides `out`  (needed by next step's [x|h])
// Weight traffic per wg per step drops 950KB -> ~245KB and all 256 CUs work.

__global__ __launch_bounds__(256, 1) void k_phase2(
    const float* __restrict__ h0,
    const int*  __restrict__ epoch_p,
    float* __restrict__ out,
    const bf16* __restrict__ WrzT, const bf16* __restrict__ WnT,
    const bf16* __restrict__ P2T,  const bf16* __restrict__ P1T,
    const bf16* __restrict__ g2T,  const bf16* __restrict__ g3T,
    const float* __restrict__ c2f, const float* __restrict__ c1f,
    const float* __restrict__ Wrz_b, const float* __restrict__ Wn_b,
    const float* __restrict__ g2_b,  const float* __restrict__ g3_b,
    const float* __restrict__ ln_g,  const float* __restrict__ ln_b,
    u64* __restrict__ rhx, u32* __restrict__ rhflag, u32* __restrict__ hflag)
{
  const int tid  = threadIdx.x;
  const int lane = tid & 63;
  const int w    = tid >> 6;        // wave 0..3
  const int n16  = lane & 15;
  const int quad = lane >> 4;
  const int g    = blockIdx.x >> 2; // batch group 0..63
  const int q    = blockIdx.x & 3;  // column quarter 0..3
  const int b0   = g * 16;
  const int c    = q * 64 + w * 16 + n16;   // own global h-col

  __shared__ __align__(16) bf16  Abuf[16][520];   // [x_t | h-then-rh]
  __shared__ __align__(16) float gbuf[16][36];
  __shared__ __align__(16) bf16  gact[16][40];
  __shared__ __align__(16) bf16  g2act[16][40];
  __shared__ float lngs[32], lnbs[32];

  if (tid < 32) { lngs[tid] = ln_g[tid]; lnbs[tid] = ln_b[tid]; }

  const int ep = *epoch_p;
  const float scale = fminf(1.0f, fmaxf(0.0f, ((float)ep - 5.0f) / 40.0f));

  const float brz_r = Wrz_b[c];
  const float brz_z = Wrz_b[256 + c];
  const float bwn   = Wn_b[c];
  const float bg3e  = g3_b[c];
  const float bg3t  = g3_b[256 + c];
  const float bg3a  = g3_b[512 + c];
  const float c2v   = c2f[c];
  const float c1v   = (w < 2) ? c1f[w * 16 + n16] : 0.0f;
  const float g2bv0 = g2_b[n16];
  const float g2bv1 = g2_b[16 + n16];

  // own-column fp32 h state: rows quad*4+r, col c
  float hreg[4];
  #pragma unroll
  for (int r = 0; r < 4; ++r)
    hreg[r] = h0[(long)(b0 + quad * 4 + r) * 256 + c];

  { // stage x_0 and full h0 (bf16) into Abuf
    const int row = tid >> 4, i = tid & 15;
    const float* hp = h0 + (long)(b0 + row) * 256 + i * 16;
    const float* xp = out + ((long)(b0 + row) * 256 + 0) * 256 + i * 16;
    bf16x8 h0v, h1v, x0v, x1v;
    #pragma unroll
    for (int j = 0; j < 8; ++j) {
      x0v[j] = (bf16)xp[j];  x1v[j] = (bf16)xp[8 + j];
      h0v[j] = (bf16)hp[j];  h1v[j] = (bf16)hp[8 + j];
    }
    *(bf16x8*)&Abuf[row][i * 16]           = x0v;
    *(bf16x8*)&Abuf[row][i * 16 + 8]       = x1v;
    *(bf16x8*)&Abuf[row][256 + i * 16]     = h0v;
    *(bf16x8*)&Abuf[row][256 + i * 16 + 8] = h1v;
  }
  __syncthreads();

  const bf16* Ab = &Abuf[n16][quad * 8];
  const int xrow = tid >> 4, xcol = (tid & 15) * 16;
  u32* rhF = rhflag + g * 16;   // 64B-strided per-group flags
  u32* hF  = hflag  + g * 16;

  for (int t = 0; t < 256; ++t) {
    const bool notlast = (t < 255);

    // prefetch x_{t+1} early (consumed after the n-GEMM; latency hidden under S2)
    f32x4 xr0 = {}, xr1 = {}, xr2 = {}, xr3 = {};
    if (notlast) {
      const float* xp = out + ((long)(b0 + xrow) * 256 + (t + 1)) * 256 + xcol;
      xr0 = *(const f32x4*)(xp);
      xr1 = *(const f32x4*)(xp + 4);
      xr2 = *(const f32x4*)(xp + 8);
      xr3 = *(const f32x4*)(xp + 12);
    }

    // ---- S2: rz (K=512 [x|h]), dh = h@P2 (K=256), g1 = h@P1 (w<2) ----
    f32x4 accr = {}, accz = {}, accdh = {}, accg = {}, accn = {};
    #pragma unroll
    for (int ks = 0; ks < 16; ++ks) {
      bf16x8 a = *(const bf16x8*)(Ab + ks * 32);
      const bf16* bp = WrzT + (long)c * 512 + ks * 32 + quad * 8;
      accr = mfma16(a, *(const bf16x8*)(bp),             accr);
      accz = mfma16(a, *(const bf16x8*)(bp + 256 * 512), accz);
    }
    #pragma unroll
    for (int ks = 0; ks < 8; ++ks) {
      bf16x8 a = *(const bf16x8*)(Ab + 256 + ks * 32);
      accdh = mfma16(a, *(const bf16x8*)(P2T + (long)c * 256 + ks * 32 + quad * 8), accdh);
      if (w < 2)
        accg = mfma16(a, *(const bf16x8*)(P1T + (w * 16 + n16) * 256 + ks * 32 + quad * 8), accg);
    }

    // ---- S3: r,z gates; publish rh quarter (packed u64: 4 bf16 rows per lane) ----
    float zv[4];
    {
      u64 pk = 0;
      #pragma unroll
      for (int r = 0; r < 4; ++r) {
        float rv = sigm(accr[r] + brz_r);
        pk |= (u64)bfbits(rv * hreg[r]) << (16 * r);
        zv[r] = sigm(accz[r] + brz_z);
      }
      __hip_atomic_store(rhx + ((long)(g * 256 + c)) * 4 + quad, pk,
                         __ATOMIC_RELAXED, __HIP_MEMORY_SCOPE_AGENT);
      if (w < 2) {
        #pragma unroll
        for (int r = 0; r < 4; ++r) gbuf[quad * 4 + r][w * 16 + n16] = accg[r] + c1v;
      }
    }
    asm volatile("s_waitcnt vmcnt(0)" ::: "memory");
    __syncthreads();                                               // bar1
    if (tid == 192)
      __hip_atomic_fetch_add(rhF, 1u, __ATOMIC_RELAXED, __HIP_MEMORY_SCOPE_AGENT);

    // ---- S4: LayerNorm(G=32)+relu (tid<16); all waves: accn x-part (ks 0..7) ----
    if (tid < 16) {
      float mu = 0, s2 = 0;
      #pragma unroll
      for (int cc = 0; cc < 32; ++cc) { float v = gbuf[tid][cc]; mu += v; s2 += v * v; }
      mu *= (1.0f / 32.0f);
      s2 = s2 * (1.0f / 32.0f) - mu * mu;
      float rstd = rsqrtf(s2 + 1e-5f);
      #pragma unroll
      for (int cc = 0; cc < 32; ++cc) {
        float gn = (gbuf[tid][cc] - mu) * rstd * lngs[cc] + lnbs[cc];
        gact[tid][cc] = (bf16)fmaxf(gn, 0.0f);
      }
    }
    #pragma unroll
    for (int ks = 0; ks < 8; ++ks) {
      bf16x8 a = *(const bf16x8*)(Ab + ks * 32);
      accn = mfma16(a, *(const bf16x8*)(WnT + (long)c * 512 + ks * 32 + quad * 8), accn);
    }
    __syncthreads();                                               // bar2

    // ---- S5: g2 (wave 0) ; spin for partners' rh (one lane of wave 3) ----
    if (w == 0) {
      bf16x8 a = *(const bf16x8*)&gact[n16][quad * 8];
      f32x4 a0 = {}, a1 = {};
      a0 = mfma16(a, *(const bf16x8*)(g2T + n16 * 32 + quad * 8), a0);
      a1 = mfma16(a, *(const bf16x8*)(g2T + (16 + n16) * 32 + quad * 8), a1);
      #pragma unroll
      for (int r = 0; r < 4; ++r) {
        int row = quad * 4 + r;
        g2act[row][n16]      = (bf16)fmaxf(a0[r] + g2bv0, 0.0f);
        g2act[row][16 + n16] = (bf16)fmaxf(a1[r] + g2bv1, 0.0f);
      }
    }
    if (tid == 193) {
      const u32 tgt = 4u * (u32)(t + 1);
      while (__hip_atomic_load(rhF, __ATOMIC_RELAXED, __HIP_MEMORY_SCOPE_AGENT) < tgt) {}
    }
    __syncthreads();                                               // bar3

    // ---- S6a: g3 (K=32); read back full rh -> Abuf[:,256:512] ----
    f32x4 acce = {}, acct = {}, acca = {};
    {
      bf16x8 a3 = *(const bf16x8*)&g2act[n16][quad * 8];
      const bf16* bp3 = g3T + (long)c * 32 + quad * 8;
      acce = mfma16(a3, *(const bf16x8*)(bp3),            acce);
      acct = mfma16(a3, *(const bf16x8*)(bp3 + 256 * 32), acct);
      acca = mfma16(a3, *(const bf16x8*)(bp3 + 512 * 32), acca);
    }
    {
      const u64* rp = rhx + ((long)(g * 256 + tid)) * 4;   // tid = global col
      #pragma unroll
      for (int j = 0; j < 4; ++j) {
        u64 v = __hip_atomic_load(rp + j, __ATOMIC_RELAXED, __HIP_MEMORY_SCOPE_AGENT);
        #pragma unroll
        for (int r = 0; r < 4; ++r)
          *(u16*)&Abuf[j * 4 + r][256 + tid] = (u16)(v >> (16 * r));
      }
    }
    __syncthreads();                                               // bar4

    // ---- S6b: accn rh-part (ks 8..15) ----
    #pragma unroll
    for (int ks = 8; ks < 16; ++ks) {
      bf16x8 a = *(const bf16x8*)(Ab + ks * 32);
      accn = mfma16(a, *(const bf16x8*)(WnT + (long)c * 512 + ks * 32 + quad * 8), accn);
    }

    // ---- S7: h update; publish h quarter via out (agent-scope stores) ----
    {
      float* op = out + ((long)(b0 + quad * 4) * 256 + t) * 256 + c;
      #pragma unroll
      for (int r = 0; r < 4; ++r) {
        float hv  = hreg[r];
        float dh  = accdh[r] + c2v;
        float eta = sigm(acce[r] + bg3e);
        float th  = fminf(softplus_(acct[r] + bg3t), 5.0f);
        float al  = sigm(acca[r] + bg3a) * scale;
        float nn  = tanh_(accn[r] + bwn);
        float s   = fminf(fmaxf(eta * hv - th * dh, -5.0f), 5.0f);
        float htl = (1.0f - al) * hv + al * s;
        float hn  = zv[r] * htl + (1.0f - zv[r]) * nn;
        hreg[r] = hn;
        __hip_atomic_store(op + (long)r * 65536, hn,
                           __ATOMIC_RELAXED, __HIP_MEMORY_SCOPE_AGENT);
      }
    }
    asm volatile("s_waitcnt vmcnt(0)" ::: "memory");
    __syncthreads();                                               // bar5
    if (tid == 192 && notlast)
      __hip_atomic_fetch_add(hF, 1u, __ATOMIC_RELAXED, __HIP_MEMORY_SCOPE_AGENT);

    // stage x_{t+1} into Abuf (n-GEMM x-reads done); overlap h-spin
    if (notlast) {
      bf16x8 v0, v1;
      #pragma unroll
      for (int j = 0; j < 4; ++j) {
        v0[j] = (bf16)xr0[j]; v0[4 + j] = (bf16)xr1[j];
        v1[j] = (bf16)xr2[j]; v1[4 + j] = (bf16)xr3[j];
      }
      *(bf16x8*)&Abuf[xrow][xcol]     = v0;
      *(bf16x8*)&Abuf[xrow][xcol + 8] = v1;
      if (tid == 193) {
        const u32 tgt = 4u * (u32)(t + 1);
        while (__hip_atomic_load(hF, __ATOMIC_RELAXED, __HIP_MEMORY_SCOPE_AGENT) < tgt) {}
      }
    }
    __syncthreads();                                               // bar6

    // read back full h_t (fp32 from out, via MALL) -> Abuf[:,256:512]
    if (notlast) {
      const u64* hp = (const u64*)(out + ((long)(b0 + xrow) * 256 + t) * 256 + xcol);
      float fv[16];
      #pragma unroll
      for (int j = 0; j < 8; ++j) {
        u64 v = __hip_atomic_load(hp + j, __ATOMIC_RELAXED, __HIP_MEMORY_SCOPE_AGENT);
        fv[2 * j]     = __builtin_bit_cast(float, (u32)(v & 0xffffffffull));
        fv[2 * j + 1] = __builtin_bit_cast(float, (u32)(v >> 32));
      }
      bf16x8 o0, o1;
      #pragma unroll
      for (int j = 0; j < 8; ++j) { o0[j] = (bf16)fv[j]; o1[j] = (bf16)fv[8 + j]; }
      *(bf16x8*)&Abuf[xrow][256 + xcol]     = o0;
      *(bf16x8*)&Abuf[xrow][256 + xcol + 8] = o1;
    }
    __syncthreads();                                               // bar7
  }
}

// ---------------- launch ----------------

extern "C" void kernel_launch(void* const* d_in, const int* in_sizes, int n_in,
                              void* d_out, int out_size, void* d_ws, size_t ws_size,
                              hipStream_t stream) {
  const float* obs    = (const float*)d_in[0];
  const float* h0     = (const float*)d_in[1];
  const int*   epoch  = (const int*)  d_in[2];
  const float* obs_W  = (const float*)d_in[3];
  const float* obs_b  = (const float*)d_in[4];
  const float* enc_W  = (const float*)d_in[5];
  const float* enc_b  = (const float*)d_in[6];
  const float* pre_W  = (const float*)d_in[7];
  const float* pre_b  = (const float*)d_in[8];
  const float* pred_W = (const float*)d_in[9];
  const float* pred_b = (const float*)d_in[10];
  const float* Wrz_W  = (const float*)d_in[11];
  const float* Wrz_b  = (const float*)d_in[12];
  const float* Wn_W   = (const float*)d_in[13];
  const float* Wn_b   = (const float*)d_in[14];
  const float* g1_W   = (const float*)d_in[15];
  const float* g1_b   = (const float*)d_in[16];
  const float* ln_g   = (const float*)d_in[17];
  const float* ln_b   = (const float*)d_in[18];
  const float* g2_W   = (const float*)d_in[19];
  const float* g2_b   = (const float*)d_in[20];
  const float* g3_W   = (const float*)d_in[21];
  const float* g3_b   = (const float*)d_in[22];
  const float* dp_W   = (const float*)d_in[23];

  bf16* W = (bf16*)d_ws;
  bf16* WrzT  = W + 0;        // 262144 elems
  bf16* WnT   = W + 262144;   // 131072
  bf16* P2T   = W + 393216;   // 65536
  bf16* P1T   = W + 458752;   // 8192
  bf16* g2T   = W + 466944;   // 1024
  bf16* g3T   = W + 467968;   // 24576
  bf16* obsWT = W + 492544;   // 16384
  bf16* encWT = W + 508928;   // 65536
  bf16* preWT = W + 574464;   // 65536  -> weights end at byte 1280000
  float* c2f  = (float*)((char*)d_ws + 1280000);  // 256 f32
  float* c1f  = (float*)((char*)d_ws + 1281024);  // 32 f32
  u64*  rhx   = (u64*) ((char*)d_ws + 1281152);   // 64*256*4 u64 = 524288 B
  u32*  rhfl  = (u32*) ((char*)d_ws + 1805440);   // 64 groups * 16 u32 = 4096 B
  u32*  hfl   = (u32*) ((char*)d_ws + 1809536);   // 4096 B (contiguous after rhfl)
  float* out = (float*)d_out;

  k_zero<<<8, 256, 0, stream>>>(rhfl, 2048);      // zero both flag arrays

  k_transpose<<<1024, 256, 0, stream>>>(Wrz_W, WrzT, 512, 512);
  k_transpose<<<512,  256, 0, stream>>>(Wn_W,  WnT,  512, 256);
  k_transpose<<<4,    256, 0, stream>>>(g2_W,  g2T,  32,  32);
  k_transpose<<<96,   256, 0, stream>>>(g3_W,  g3T,  32,  768);
  k_transpose<<<64,   256, 0, stream>>>(obs_W, obsWT, 64, 256);
  k_transpose<<<256,  256, 0, stream>>>(enc_W, encWT, 256, 256);
  k_transpose<<<256,  256, 0, stream>>>(pre_W, preWT, 256, 256);
  k_p2<<<256, 256, 0, stream>>>(pred_W, dp_W, P2T);
  k_p1<<<32,  256, 0, stream>>>(pred_W, g1_W, P1T);
  k_cvec<<<1, 256, 0, stream>>>(pred_b, dp_W, g1_W, g1_b, c2f, c1f);

  k_phase1<<<4096, 256, 0, stream>>>(obs, obsWT, encWT, preWT, obs_b, enc_b, pre_b, out);
  k_phase2<<<256, 256, 0, stream>>>(h0, epoch, out, WrzT, WnT, P2T, P1T, g2T, g3T,
                                    c2f, c1f, Wrz_b, Wn_b, g2_b, g3_b, ln_g, ln_b,
                                    rhx, rhfl, hfl);

  (void)in_sizes; (void)n_in; (void)out_size; (void)ws_size;
}